// Round 13
// baseline (67.731 us; speedup 1.0000x reference)
//
#include <hip/hip_runtime.h>
#include <hip/hip_bf16.h>

#define EPS 1e-6f

typedef __attribute__((ext_vector_type(4))) float f32x4;

// pack 4 floats into 4 fp8-e4m3 bytes (k-order: x->byte0 .. w->byte3)
__device__ inline unsigned int pack_fp8x4(float x, float y, float z, float w) {
  int r = 0;
  r = __builtin_amdgcn_cvt_pk_fp8_f32(x, y, r, false);  // bytes 0,1
  r = __builtin_amdgcn_cvt_pk_fp8_f32(z, w, r, true);   // bytes 2,3
  return (unsigned int)r;
}

// ---------------------------------------------------------------------------
// Kernel A: per-speaker precompute (unchanged from round 11).
// ---------------------------------------------------------------------------
__global__ void __launch_bounds__(192) ge2e_pre(
    const float* __restrict__ dv, unsigned int* __restrict__ a8u,
    unsigned int* __restrict__ c8u, float* __restrict__ simown,
    float* __restrict__ rowsum, float* __restrict__ out) {
  const int n = blockIdx.x, t = threadIdx.x;
  if (n == 0 && t == 0) out[0] = 0.f;
  const float* base = dv + (size_t)n * 7680;
  float4 v[10];
  float4 s4 = make_float4(0.f, 0.f, 0.f, 0.f);
#pragma unroll
  for (int m = 0; m < 10; ++m) {
    v[m] = *reinterpret_cast<const float4*>(&base[m * 768 + 4 * t]);
    s4.x += v[m].x; s4.y += v[m].y; s4.z += v[m].z; s4.w += v[m].w;
  }
  float part[21];
#pragma unroll
  for (int m = 0; m < 10; ++m) {
    part[m]      = v[m].x * s4.x + v[m].y * s4.y + v[m].z * s4.z + v[m].w * s4.w;
    part[10 + m] = v[m].x * v[m].x + v[m].y * v[m].y + v[m].z * v[m].z + v[m].w * v[m].w;
  }
  part[20] = s4.x * s4.x + s4.y * s4.y + s4.z * s4.z + s4.w * s4.w;
#pragma unroll
  for (int k = 0; k < 21; ++k) {
#pragma unroll
    for (int off = 32; off >= 1; off >>= 1) part[k] += __shfl_xor(part[k], off);
  }
  __shared__ float red[3][21];
  __shared__ float bc[21];
  const int lane = t & 63, wid = t >> 6;
  if (lane == 0) {
#pragma unroll
    for (int k = 0; k < 21; ++k) red[wid][k] = part[k];
  }
  __syncthreads();
  if (t < 21) bc[t] = red[0][t] + red[1][t] + red[2][t];
  __syncthreads();
  const float ss = bc[20];
  const float rc = 1.0f / fmaxf(sqrtf(ss), 10.0f * EPS);
  c8u[n * 192 + t] = pack_fp8x4(s4.x * rc, s4.y * rc, s4.z * rc, s4.w * rc);
#pragma unroll
  for (int m = 0; m < 10; ++m) {
    float rd = 1.0f / fmaxf(sqrtf(bc[10 + m]), EPS);
    a8u[(size_t)(n * 10 + m) * 192 + t] =
        pack_fp8x4(v[m].x * rd, v[m].y * rd, v[m].z * rd, v[m].w * rd);
  }
  if (t < 10) {
    float dot = bc[t], sq = bc[10 + t];
    float dn = fmaxf(sqrtf(sq), EPS);
    float en = fmaxf(sqrtf(fmaxf(ss - 2.f * dot + sq, 0.f)) * (1.0f / 9.0f), EPS);
    simown[n * 10 + t] = ((dot - sq) * (1.0f / 9.0f)) / (dn * en);
    rowsum[n * 10 + t] = 0.f;
  }
}

// ---------------------------------------------------------------------------
// Kernel B: round-11 gemm, byte-identical (tile 320x64, 8 waves, superstep
// counted-vmcnt, 512 blocks = 2/CU). Feeds the REAL rowsum.
// ---------------------------------------------------------------------------
__global__ void __launch_bounds__(512, 4) ge2e_gemm(
    const unsigned char* __restrict__ a8, const unsigned char* __restrict__ c8,
    const float* __restrict__ simown, const float* __restrict__ wp,
    float* __restrict__ rowsum) {
  __shared__ __align__(16) unsigned char As[2][20480];
  __shared__ __align__(16) unsigned char Bs[2][4096];
  const int t = threadIdx.x;
  const int lane = t & 63, wid = t >> 6;
  const int bx = blockIdx.x;
  const int wg = (bx & 7) * 64 + (bx >> 3);
  const int rb = wg >> 4, cb = wg & 15;
  const int row0 = rb * 320, col0 = cb * 64;
  const int wm = wid >> 1, wn = wid & 1;
  const int l15 = lane & 15, lg = lane >> 4;
  const int srow = lane >> 2;
  const int sk = (lane & 3) ^ ((lane >> 3) & 3);

  f32x4 acc[5][2];
#pragma unroll
  for (int i = 0; i < 5; ++i)
#pragma unroll
    for (int j = 0; j < 2; ++j) acc[i][j] = (f32x4){0.f, 0.f, 0.f, 0.f};

  auto STAGE = [&](int buf, int ks) {
#pragma unroll
    for (int j = 0; j < 3; ++j) {
      const int g = wid * 3 + j;
      if (g < 20) {
        const unsigned char* src =
            a8 + (size_t)(row0 + g * 16 + srow) * 768 + ks * 64 + sk * 16;
        __builtin_amdgcn_global_load_lds(
            (const __attribute__((address_space(1))) unsigned int*)src,
            (__attribute__((address_space(3))) unsigned int*)&As[buf][g * 1024],
            16, 0, 0);
      } else {
        const unsigned char* src =
            c8 + (size_t)(col0 + (g - 20) * 16 + srow) * 768 + ks * 64 + sk * 16;
        __builtin_amdgcn_global_load_lds(
            (const __attribute__((address_space(1))) unsigned int*)src,
            (__attribute__((address_space(3))) unsigned int*)&Bs[buf][(g - 20) * 1024],
            16, 0, 0);
      }
    }
  };
  auto ldA = [&](int buf, int kh, int fr) -> long long {
    const int row = wm * 80 + fr * 16 + l15;
    const int slot = (kh * 2 + (lg >> 1)) ^ ((row >> 1) & 3);
    return *(const long long*)&As[buf][row * 64 + slot * 16 + (lg & 1) * 8];
  };
  auto ldB = [&](int buf, int kh, int fc) -> long long {
    const int row = wn * 32 + fc * 16 + l15;
    const int slot = (kh * 2 + (lg >> 1)) ^ ((row >> 1) & 3);
    return *(const long long*)&Bs[buf][row * 64 + slot * 16 + (lg & 1) * 8];
  };
  auto COMPUTE = [&](int buf) {
    long long af[5][2], bf[2][2];
#pragma unroll
    for (int fc = 0; fc < 2; ++fc)
#pragma unroll
      for (int kh = 0; kh < 2; ++kh) bf[fc][kh] = ldB(buf, kh, fc);
#pragma unroll
    for (int fr = 0; fr < 5; ++fr)
#pragma unroll
      for (int kh = 0; kh < 2; ++kh) af[fr][kh] = ldA(buf, kh, fr);
    __builtin_amdgcn_s_setprio(1);
#pragma unroll
    for (int kh = 0; kh < 2; ++kh)
#pragma unroll
      for (int fr = 0; fr < 5; ++fr)
#pragma unroll
        for (int fc = 0; fc < 2; ++fc)
          acc[fr][fc] = __builtin_amdgcn_mfma_f32_16x16x32_fp8_fp8(
              af[fr][kh], bf[fc][kh], acc[fr][fc], 0, 0, 0);
    __builtin_amdgcn_s_setprio(0);
  };

  STAGE(0, 0);
#pragma unroll
  for (int s = 0; s < 12; ++s) {
    if (s < 11) {
      STAGE((s + 1) & 1, s + 1);
      asm volatile("s_waitcnt vmcnt(3)" ::: "memory");
    } else {
      asm volatile("s_waitcnt vmcnt(0)" ::: "memory");
    }
    __builtin_amdgcn_s_barrier();
    COMPUTE(s & 1);
    if (s < 11) __builtin_amdgcn_s_barrier();
  }

  const float wv = wp[0];
  const int R0 = row0 + wm * 80, C0 = col0 + wn * 32;
#pragma unroll
  for (int fr = 0; fr < 5; ++fr) {
#pragma unroll
    for (int r = 0; r < 4; ++r) {
      const int grow = R0 + fr * 16 + lg * 4 + r;
      const int ownc = grow / 10;
      float sm = 0.f;
#pragma unroll
      for (int fc = 0; fc < 2; ++fc) {
        const int gcol = C0 + fc * 16 + l15;
        float vv = wv * acc[fr][fc][r];
        if (gcol == ownc) vv = wv * simown[grow];
        sm += __expf(vv);
      }
#pragma unroll
      for (int off = 1; off < 16; off <<= 1) sm += __shfl_xor(sm, off, 16);
      if (l15 == 0) atomicAdd(&rowsum[grow], sm);
    }
  }
}

// ---------------------------------------------------------------------------
// Kernel B-test (MEASUREMENT): 4-wave 128x64-tile superstep gemm at 5
// blocks/CU (1280 blocks x 256 thr, 20 waves/CU TLP) -- candidate structure
// combining counted-vmcnt superstep with high cross-block TLP. Writes to
// SCRATCH rowsum2 (never read; d_out unaffected). total13 - total11 gives
// this kernel's true duration, bypassing the fill-polluted rocprof top-5.
// ---------------------------------------------------------------------------
__global__ void __launch_bounds__(256, 5) ge2e_gemm4(
    const unsigned char* __restrict__ a8, const unsigned char* __restrict__ c8,
    const float* __restrict__ simown, const float* __restrict__ wp,
    float* __restrict__ rowsum2) {
  __shared__ __align__(16) unsigned char As[2][8192];  // 128 rows x 64B
  __shared__ __align__(16) unsigned char Bs[2][4096];  //  64 rows x 64B
  const int t = threadIdx.x;
  const int lane = t & 63, wid = t >> 6;   // 4 waves
  const int bx = blockIdx.x;
  const int wg = (bx & 7) * 160 + (bx >> 3);  // bijective XCD swizzle, 1280=8x160
  const int rb = wg >> 4, cb = wg & 15;       // 80 rowblocks x 16 colblocks
  const int row0 = rb * 128, col0 = cb * 64;
  const int wm = wid >> 1, wn = wid & 1;      // wave tile: 64 rows x 32 cols
  const int l15 = lane & 15, lg = lane >> 4;
  const int srow = lane >> 2;
  const int sk = (lane & 3) ^ ((lane >> 3) & 3);

  f32x4 acc[4][2];
#pragma unroll
  for (int i = 0; i < 4; ++i)
#pragma unroll
    for (int j = 0; j < 2; ++j) acc[i][j] = (f32x4){0.f, 0.f, 0.f, 0.f};

  auto STAGE = [&](int buf, int ks) {
#pragma unroll
    for (int j = 0; j < 3; ++j) {
      const int g = wid * 3 + j;  // 0..11: 8 A-segs + 4 B-segs
      if (g < 8) {
        const unsigned char* src =
            a8 + (size_t)(row0 + g * 16 + srow) * 768 + ks * 64 + sk * 16;
        __builtin_amdgcn_global_load_lds(
            (const __attribute__((address_space(1))) unsigned int*)src,
            (__attribute__((address_space(3))) unsigned int*)&As[buf][g * 1024],
            16, 0, 0);
      } else {
        const unsigned char* src =
            c8 + (size_t)(col0 + (g - 8) * 16 + srow) * 768 + ks * 64 + sk * 16;
        __builtin_amdgcn_global_load_lds(
            (const __attribute__((address_space(1))) unsigned int*)src,
            (__attribute__((address_space(3))) unsigned int*)&Bs[buf][(g - 8) * 1024],
            16, 0, 0);
      }
    }
  };
  auto ldA = [&](int buf, int kh, int fr) -> long long {
    const int row = wm * 64 + fr * 16 + l15;
    const int slot = (kh * 2 + (lg >> 1)) ^ ((row >> 1) & 3);
    return *(const long long*)&As[buf][row * 64 + slot * 16 + (lg & 1) * 8];
  };
  auto ldB = [&](int buf, int kh, int fc) -> long long {
    const int row = wn * 32 + fc * 16 + l15;
    const int slot = (kh * 2 + (lg >> 1)) ^ ((row >> 1) & 3);
    return *(const long long*)&Bs[buf][row * 64 + slot * 16 + (lg & 1) * 8];
  };
  auto COMPUTE = [&](int buf) {
#pragma unroll
    for (int kh = 0; kh < 2; ++kh) {   // per-kh frag loads keep VGPR < 102 cap
      long long af[4], bf[2];
#pragma unroll
      for (int fc = 0; fc < 2; ++fc) bf[fc] = ldB(buf, kh, fc);
#pragma unroll
      for (int fr = 0; fr < 4; ++fr) af[fr] = ldA(buf, kh, fr);
      __builtin_amdgcn_s_setprio(1);
#pragma unroll
      for (int fr = 0; fr < 4; ++fr)
#pragma unroll
        for (int fc = 0; fc < 2; ++fc)
          acc[fr][fc] = __builtin_amdgcn_mfma_f32_16x16x32_fp8_fp8(
              af[fr], bf[fc], acc[fr][fc], 0, 0, 0);
      __builtin_amdgcn_s_setprio(0);
    }
  };

  STAGE(0, 0);
#pragma unroll
  for (int s = 0; s < 12; ++s) {
    if (s < 11) {
      STAGE((s + 1) & 1, s + 1);
      asm volatile("s_waitcnt vmcnt(3)" ::: "memory");
    } else {
      asm volatile("s_waitcnt vmcnt(0)" ::: "memory");
    }
    __builtin_amdgcn_s_barrier();
    COMPUTE(s & 1);
    if (s < 11) __builtin_amdgcn_s_barrier();
  }

  const float wv = wp[0];
  const int R0 = row0 + wm * 64, C0 = col0 + wn * 32;
#pragma unroll
  for (int fr = 0; fr < 4; ++fr) {
#pragma unroll
    for (int r = 0; r < 4; ++r) {
      const int grow = R0 + fr * 16 + lg * 4 + r;
      const int ownc = grow / 10;
      float sm = 0.f;
#pragma unroll
      for (int fc = 0; fc < 2; ++fc) {
        const int gcol = C0 + fc * 16 + l15;
        float vv = wv * acc[fr][fc][r];
        if (gcol == ownc) vv = wv * simown[grow];
        sm += __expf(vv);
      }
#pragma unroll
      for (int off = 1; off < 16; off <<= 1) sm += __shfl_xor(sm, off, 16);
      if (l15 == 0) atomicAdd(&rowsum2[grow], sm);  // scratch, never read
    }
  }
}

// ---------------------------------------------------------------------------
// Kernel C: loss_i = log(rowsum_i) - w*simown_i; sum over 10240 into d_out.
// ---------------------------------------------------------------------------
__global__ void __launch_bounds__(256) ge2e_final(
    const float* __restrict__ rowsum, const float* __restrict__ simown,
    const float* __restrict__ wp, float* __restrict__ out) {
  const int i = blockIdx.x * 256 + threadIdx.x;
  const float wv = wp[0];
  float loss = logf(rowsum[i]) - wv * simown[i];
#pragma unroll
  for (int off = 32; off >= 1; off >>= 1) loss += __shfl_xor(loss, off);
  __shared__ float red[4];
  const int lane = threadIdx.x & 63, wid = threadIdx.x >> 6;
  if (lane == 0) red[wid] = loss;
  __syncthreads();
  if (threadIdx.x == 0) atomicAdd(out, red[0] + red[1] + red[2] + red[3]);
}

extern "C" void kernel_launch(void* const* d_in, const int* in_sizes, int n_in,
                              void* d_out, int out_size, void* d_ws, size_t ws_size,
                              hipStream_t stream) {
  (void)in_sizes; (void)n_in; (void)out_size; (void)ws_size;
  const float* dv = (const float*)d_in[0];
  const float* wp = (const float*)d_in[1];

  unsigned char* a8 = (unsigned char*)d_ws;                         // 7,864,320 B
  unsigned char* c8 = (unsigned char*)d_ws + 7864320;               //   786,432 B
  float* simown  = (float*)((char*)d_ws + 8650752);                 //    40,960 B
  float* rowsum  = (float*)((char*)d_ws + 8691712);                 //    40,960 B
  float* rowsum2 = (float*)((char*)d_ws + 8732672);                 //    40,960 B (scratch)
  float* out = (float*)d_out;

  ge2e_pre<<<1024, 192, 0, stream>>>(dv, (unsigned int*)a8, (unsigned int*)c8,
                                     simown, rowsum, out);
  ge2e_gemm<<<512, 512, 0, stream>>>(a8, c8, simown, wp, rowsum);
  ge2e_gemm4<<<1280, 256, 0, stream>>>(a8, c8, simown, wp, rowsum2);  // measurement
  ge2e_final<<<40, 256, 0, stream>>>(rowsum, simown, wp, out);
}

// Round 14
// 45.809 us; speedup vs baseline: 1.4785x; 1.4785x over previous
//
#include <hip/hip_runtime.h>
#include <hip/hip_bf16.h>

#define EPS 1e-6f

typedef __attribute__((ext_vector_type(4))) float f32x4;

// pack 4 floats into 4 fp8-e4m3 bytes (k-order: x->byte0 .. w->byte3)
__device__ inline unsigned int pack_fp8x4(float x, float y, float z, float w) {
  int r = 0;
  r = __builtin_amdgcn_cvt_pk_fp8_f32(x, y, r, false);  // bytes 0,1
  r = __builtin_amdgcn_cvt_pk_fp8_f32(z, w, r, true);   // bytes 2,3
  return (unsigned int)r;
}

// ---------------------------------------------------------------------------
// Kernel A: per-speaker precompute (192 threads, float4-vectorized).
// Writes: a8[i][d] = fp8e4m3(dvec[i][d]/||dvec_i||)      (10240 x 768)
//         c8[n][d] = fp8e4m3(ctrd[n][d]/||ctrd_n||)      (1024 x 768)
//         simown[i] = fp32 cosine(dvec_i, excl-centroid) (10240, exact fp32)
// Also zeroes rowsum[10240], the gemm completion counter, and out[0].
// ---------------------------------------------------------------------------
__global__ void __launch_bounds__(192) ge2e_pre(
    const float* __restrict__ dv, unsigned int* __restrict__ a8u,
    unsigned int* __restrict__ c8u, float* __restrict__ simown,
    float* __restrict__ rowsum, int* __restrict__ cnt,
    float* __restrict__ out) {
  const int n = blockIdx.x, t = threadIdx.x;  // t in [0,192): owns dims 4t..4t+3
  if (n == 0 && t == 0) { out[0] = 0.f; cnt[0] = 0; }  // graph-replay reset
  const float* base = dv + (size_t)n * 7680;
  float4 v[10];
  float4 s4 = make_float4(0.f, 0.f, 0.f, 0.f);
#pragma unroll
  for (int m = 0; m < 10; ++m) {
    v[m] = *reinterpret_cast<const float4*>(&base[m * 768 + 4 * t]);
    s4.x += v[m].x; s4.y += v[m].y; s4.z += v[m].z; s4.w += v[m].w;
  }
  float part[21];
#pragma unroll
  for (int m = 0; m < 10; ++m) {
    part[m]      = v[m].x * s4.x + v[m].y * s4.y + v[m].z * s4.z + v[m].w * s4.w;
    part[10 + m] = v[m].x * v[m].x + v[m].y * v[m].y + v[m].z * v[m].z + v[m].w * v[m].w;
  }
  part[20] = s4.x * s4.x + s4.y * s4.y + s4.z * s4.z + s4.w * s4.w;
#pragma unroll
  for (int k = 0; k < 21; ++k) {
#pragma unroll
    for (int off = 32; off >= 1; off >>= 1) part[k] += __shfl_xor(part[k], off);
  }
  __shared__ float red[3][21];
  __shared__ float bc[21];
  const int lane = t & 63, wid = t >> 6;
  if (lane == 0) {
#pragma unroll
    for (int k = 0; k < 21; ++k) red[wid][k] = part[k];
  }
  __syncthreads();
  if (t < 21) bc[t] = red[0][t] + red[1][t] + red[2][t];
  __syncthreads();
  const float ss = bc[20];
  // centroid = sums/10; cnorm = max(|ctrd|,eps) -> normalize sums by max(|sums|,10eps)
  const float rc = 1.0f / fmaxf(sqrtf(ss), 10.0f * EPS);
  c8u[n * 192 + t] = pack_fp8x4(s4.x * rc, s4.y * rc, s4.z * rc, s4.w * rc);
#pragma unroll
  for (int m = 0; m < 10; ++m) {
    float rd = 1.0f / fmaxf(sqrtf(bc[10 + m]), EPS);
    a8u[(size_t)(n * 10 + m) * 192 + t] =
        pack_fp8x4(v[m].x * rd, v[m].y * rd, v[m].z * rd, v[m].w * rd);
  }
  if (t < 10) {
    float dot = bc[t], sq = bc[10 + t];
    float dn = fmaxf(sqrtf(sq), EPS);
    float en = fmaxf(sqrtf(fmaxf(ss - 2.f * dot + sq, 0.f)) * (1.0f / 9.0f), EPS);
    simown[n * 10 + t] = ((dot - sq) * (1.0f / 9.0f)) / (dn * en);
    rowsum[n * 10 + t] = 0.f;  // accumulated by ge2e_gemm atomics
  }
}

// ---------------------------------------------------------------------------
// Kernel B: fp8 MFMA GEMM (10240x1024x768), round-11's proven structure
// (tile 320x64, 8 waves 4Mx2N, counted-vmcnt superstep, 512 blocks = 2/CU,
// XOR-swizzled LDS, bijective XCD swizzle) PLUS fused finalization:
// after each block's rowsum atomics drain (__syncthreads -> vmcnt(0)), t0
// bumps a device-scope counter; the 512th block re-reads rowsum via
// atomicAdd(p, 0.0f) (device-scope => cross-XCD coherent, G16), computes
// loss_i = log(rowsum_i) - w*simown_i, reduces, stores out[0]. Saves one
// dispatch + inter-kernel gap. Deterministic by value (block order varies,
// result doesn't -- same property as the atomic rowsum accumulation).
// ---------------------------------------------------------------------------
__global__ void __launch_bounds__(512, 4) ge2e_gemm(
    const unsigned char* __restrict__ a8, const unsigned char* __restrict__ c8,
    const float* __restrict__ simown, const float* __restrict__ wp,
    float* __restrict__ rowsum, int* __restrict__ cnt,
    float* __restrict__ out) {
  __shared__ __align__(16) unsigned char As[2][20480];  // [buf] 320 rows x 64B
  __shared__ __align__(16) unsigned char Bs[2][4096];   // [buf]  64 rows x 64B
  const int t = threadIdx.x;
  const int lane = t & 63, wid = t >> 6;
  const int bx = blockIdx.x;
  const int wg = (bx & 7) * 64 + (bx >> 3);  // bijective XCD swizzle, 512=8x64
  const int rb = wg >> 4, cb = wg & 15;
  const int row0 = rb * 320, col0 = cb * 64;
  const int wm = wid >> 1, wn = wid & 1;     // wave tile: 80 rows x 32 cols
  const int l15 = lane & 15, lg = lane >> 4;
  const int srow = lane >> 2;
  const int sk = (lane & 3) ^ ((lane >> 3) & 3);  // inverse-swizzled src slot

  f32x4 acc[5][2];
#pragma unroll
  for (int i = 0; i < 5; ++i)
#pragma unroll
    for (int j = 0; j < 2; ++j) acc[i][j] = (f32x4){0.f, 0.f, 0.f, 0.f};

  auto STAGE = [&](int buf, int ks) {
#pragma unroll
    for (int j = 0; j < 3; ++j) {
      const int g = wid * 3 + j;  // 0..23, wave-uniform
      if (g < 20) {               // A: rows g*16..g*16+15
        const unsigned char* src =
            a8 + (size_t)(row0 + g * 16 + srow) * 768 + ks * 64 + sk * 16;
        __builtin_amdgcn_global_load_lds(
            (const __attribute__((address_space(1))) unsigned int*)src,
            (__attribute__((address_space(3))) unsigned int*)&As[buf][g * 1024],
            16, 0, 0);
      } else {                    // B: rows (g-20)*16..+15
        const unsigned char* src =
            c8 + (size_t)(col0 + (g - 20) * 16 + srow) * 768 + ks * 64 + sk * 16;
        __builtin_amdgcn_global_load_lds(
            (const __attribute__((address_space(1))) unsigned int*)src,
            (__attribute__((address_space(3))) unsigned int*)&Bs[buf][(g - 20) * 1024],
            16, 0, 0);
      }
    }
  };
  auto ldA = [&](int buf, int kh, int fr) -> long long {
    const int row = wm * 80 + fr * 16 + l15;
    const int slot = (kh * 2 + (lg >> 1)) ^ ((row >> 1) & 3);
    return *(const long long*)&As[buf][row * 64 + slot * 16 + (lg & 1) * 8];
  };
  auto ldB = [&](int buf, int kh, int fc) -> long long {
    const int row = wn * 32 + fc * 16 + l15;
    const int slot = (kh * 2 + (lg >> 1)) ^ ((row >> 1) & 3);
    return *(const long long*)&Bs[buf][row * 64 + slot * 16 + (lg & 1) * 8];
  };
  auto COMPUTE = [&](int buf) {
    long long af[5][2], bf[2][2];
#pragma unroll
    for (int fc = 0; fc < 2; ++fc)
#pragma unroll
      for (int kh = 0; kh < 2; ++kh) bf[fc][kh] = ldB(buf, kh, fc);
#pragma unroll
    for (int fr = 0; fr < 5; ++fr)
#pragma unroll
      for (int kh = 0; kh < 2; ++kh) af[fr][kh] = ldA(buf, kh, fr);
    __builtin_amdgcn_s_setprio(1);
#pragma unroll
    for (int kh = 0; kh < 2; ++kh)
#pragma unroll
      for (int fr = 0; fr < 5; ++fr)
#pragma unroll
        for (int fc = 0; fc < 2; ++fc)
          acc[fr][fc] = __builtin_amdgcn_mfma_f32_16x16x32_fp8_fp8(
              af[fr][kh], bf[fc][kh], acc[fr][fc], 0, 0, 0);
    __builtin_amdgcn_s_setprio(0);
  };

  STAGE(0, 0);
#pragma unroll
  for (int s = 0; s < 12; ++s) {
    if (s < 11) {
      STAGE((s + 1) & 1, s + 1);  // buf free per iter s-1's trailing barrier
      asm volatile("s_waitcnt vmcnt(3)" ::: "memory");  // tile s landed
    } else {
      asm volatile("s_waitcnt vmcnt(0)" ::: "memory");
    }
    __builtin_amdgcn_s_barrier();
    COMPUTE(s & 1);
    if (s < 11) __builtin_amdgcn_s_barrier();  // all waves done with buf[s&1]
  }

  // Epilogue: vv = w*cos (diagonal: fp32 sim_own); rowsum[grow] += sum_j exp(vv)
  const float wv = wp[0];
  const int R0 = row0 + wm * 80, C0 = col0 + wn * 32;
#pragma unroll
  for (int fr = 0; fr < 5; ++fr) {
#pragma unroll
    for (int r = 0; r < 4; ++r) {
      const int grow = R0 + fr * 16 + lg * 4 + r;
      const int ownc = grow / 10;  // own speaker column
      float sm = 0.f;
#pragma unroll
      for (int fc = 0; fc < 2; ++fc) {
        const int gcol = C0 + fc * 16 + l15;
        float vv = wv * acc[fr][fc][r];
        if (gcol == ownc) vv = wv * simown[grow];
        sm += __expf(vv);
      }
#pragma unroll
      for (int off = 1; off < 16; off <<= 1) sm += __shfl_xor(sm, off, 16);
      if (l15 == 0) atomicAdd(&rowsum[grow], sm);
    }
  }

  // ---- fused finalization (last block only) ----
  __syncthreads();  // drains vmcnt: this block's rowsum atomics complete
  __shared__ int isLast;
  if (t == 0) isLast = (atomicAdd(cnt, 1) == 511);
  __syncthreads();
  if (isLast) {
    float loss = 0.f;
#pragma unroll
    for (int j = 0; j < 20; ++j) {
      const int i = j * 512 + t;  // coalesced over 10240 rows
      const float rs = atomicAdd(&rowsum[i], 0.0f);  // device-scope coherent read
      loss += logf(rs) - wv * simown[i];
    }
#pragma unroll
    for (int off = 32; off >= 1; off >>= 1) loss += __shfl_xor(loss, off);
    __shared__ float redf[8];
    if ((t & 63) == 0) redf[t >> 6] = loss;
    __syncthreads();
    if (t == 0) {
      float s = 0.f;
#pragma unroll
      for (int w = 0; w < 8; ++w) s += redf[w];
      out[0] = s;
    }
  }
}

extern "C" void kernel_launch(void* const* d_in, const int* in_sizes, int n_in,
                              void* d_out, int out_size, void* d_ws, size_t ws_size,
                              hipStream_t stream) {
  (void)in_sizes; (void)n_in; (void)out_size; (void)ws_size;
  const float* dv = (const float*)d_in[0];
  const float* wp = (const float*)d_in[1];
  // d_in[2] (bias b) cancels exactly in -log_softmax[own]; unused.

  unsigned char* a8 = (unsigned char*)d_ws;                         // 7,864,320 B
  unsigned char* c8 = (unsigned char*)d_ws + 7864320;               //   786,432 B
  float* simown = (float*)((char*)d_ws + 8650752);                  //    40,960 B
  float* rowsum = (float*)((char*)d_ws + 8691712);                  //    40,960 B
  int*   cnt    = (int*)  ((char*)d_ws + 8732672);                  //         4 B
  float* out = (float*)d_out;

  ge2e_pre<<<1024, 192, 0, stream>>>(dv, (unsigned int*)a8, (unsigned int*)c8,
                                     simown, rowsum, cnt, out);
  ge2e_gemm<<<512, 512, 0, stream>>>(a8, c8, simown, wp, rowsum, cnt, out);
}

// Round 15
// 41.891 us; speedup vs baseline: 1.6168x; 1.0935x over previous
//
#include <hip/hip_runtime.h>
#include <hip/hip_bf16.h>

#define EPS 1e-6f

typedef __attribute__((ext_vector_type(4))) float f32x4;

// pack 4 floats into 4 fp8-e4m3 bytes (k-order: x->byte0 .. w->byte3)
__device__ inline unsigned int pack_fp8x4(float x, float y, float z, float w) {
  int r = 0;
  r = __builtin_amdgcn_cvt_pk_fp8_f32(x, y, r, false);  // bytes 0,1
  r = __builtin_amdgcn_cvt_pk_fp8_f32(z, w, r, true);   // bytes 2,3
  return (unsigned int)r;
}

// ---------------------------------------------------------------------------
// Kernel A (round-15): ONE WAVE PER SPEAKER. 256 blocks x 256 threads
// (4 speakers/block, lane owns dims 12*lane..12*lane+11).
//   * Shuffle work cut 3x vs the 192-thread version: 20 butterflies x 6
//     stages per SPEAKER (was 21 x 6 x 3 waves + LDS combine + 2 barriers).
//     r2->r3 forensics says pre is shuffle-bound, not load-bound.
//   * ss = sum.sum recovered algebraically: ss = sum_m part[m] AFTER
//     reduction (dot(v_m,sum) summed over m = dot(sum,sum)) -- 21st
//     reduction eliminated.
//   * 30 independent float4 loads/thread saturate BW at 1 wave/SIMD.
// Writes a8 (fp8 normalized rows), c8 (fp8 normalized centroids),
// simown (exact fp32), zeroes rowsum and out[0].
// ---------------------------------------------------------------------------
__global__ void __launch_bounds__(256) ge2e_pre(
    const float* __restrict__ dv, unsigned int* __restrict__ a8u,
    unsigned int* __restrict__ c8u, float* __restrict__ simown,
    float* __restrict__ rowsum, float* __restrict__ out) {
  const int t = threadIdx.x;
  const int wave = t >> 6, lane = t & 63;
  const int n = blockIdx.x * 4 + wave;           // speaker 0..1023
  const int gid = blockIdx.x * 256 + t;
  if (gid < 10240) rowsum[gid] = 0.f;            // accumulated by gemm atomics
  if (gid == 0) out[0] = 0.f;
  const float* base = dv + (size_t)n * 7680 + lane * 12;

  f32x4 v[10][3];
  f32x4 s4[3] = {{0.f, 0.f, 0.f, 0.f}, {0.f, 0.f, 0.f, 0.f}, {0.f, 0.f, 0.f, 0.f}};
#pragma unroll
  for (int m = 0; m < 10; ++m)
#pragma unroll
    for (int j = 0; j < 3; ++j) {
      v[m][j] = *reinterpret_cast<const f32x4*>(base + m * 768 + j * 4);
      s4[j] += v[m][j];
    }
  float part[20];
#pragma unroll
  for (int m = 0; m < 10; ++m) {
    float d = 0.f, q = 0.f;
#pragma unroll
    for (int j = 0; j < 3; ++j) {
#pragma unroll
      for (int c = 0; c < 4; ++c) {
        d += v[m][j][c] * s4[j][c];
        q += v[m][j][c] * v[m][j][c];
      }
    }
    part[m] = d;
    part[10 + m] = q;
  }
  // 64-lane butterfly; 20 independent chains give the ILP to hide ds latency
#pragma unroll
  for (int k = 0; k < 20; ++k) {
#pragma unroll
    for (int off = 32; off >= 1; off >>= 1) part[k] += __shfl_xor(part[k], off);
  }
  const float ss = ((part[0] + part[1]) + (part[2] + part[3])) +
                   ((part[4] + part[5]) + (part[6] + part[7])) +
                   (part[8] + part[9]);  // = dot(sum,sum), exact identity
  // centroid = sums/10; cnorm = max(|ctrd|,eps) -> normalize by max(|sums|,10eps)
  const float rc = 1.0f / fmaxf(sqrtf(ss), 10.0f * EPS);
#pragma unroll
  for (int p = 0; p < 3; ++p)
    c8u[n * 192 + lane * 3 + p] =
        pack_fp8x4(s4[p][0] * rc, s4[p][1] * rc, s4[p][2] * rc, s4[p][3] * rc);
#pragma unroll
  for (int m = 0; m < 10; ++m) {
    const float rd = 1.0f / fmaxf(sqrtf(part[10 + m]), EPS);
#pragma unroll
    for (int p = 0; p < 3; ++p)
      a8u[(size_t)(n * 10 + m) * 192 + lane * 3 + p] =
          pack_fp8x4(v[m][p][0] * rd, v[m][p][1] * rd,
                     v[m][p][2] * rd, v[m][p][3] * rd);
  }
  if (lane < 10) {
    const float dot = part[lane], sq = part[10 + lane];
    const float dn = fmaxf(sqrtf(sq), EPS);
    const float en = fmaxf(sqrtf(fmaxf(ss - 2.f * dot + sq, 0.f)) * (1.0f / 9.0f), EPS);
    simown[n * 10 + lane] = ((dot - sq) * (1.0f / 9.0f)) / (dn * en);
  }
}

// ---------------------------------------------------------------------------
// Kernel B: fp8 MFMA GEMM, round-11 structure byte-identical (tile 320x64,
// 8 waves 4Mx2N, counted-vmcnt superstep, 512 blocks = 2/CU, XOR-swizzled
// LDS both sides, bijective XCD swizzle). Best measured pipeline: 43.59us.
// ---------------------------------------------------------------------------
__global__ void __launch_bounds__(512, 4) ge2e_gemm(
    const unsigned char* __restrict__ a8, const unsigned char* __restrict__ c8,
    const float* __restrict__ simown, const float* __restrict__ wp,
    float* __restrict__ rowsum) {
  __shared__ __align__(16) unsigned char As[2][20480];  // [buf] 320 rows x 64B
  __shared__ __align__(16) unsigned char Bs[2][4096];   // [buf]  64 rows x 64B
  const int t = threadIdx.x;
  const int lane = t & 63, wid = t >> 6;
  const int bx = blockIdx.x;
  const int wg = (bx & 7) * 64 + (bx >> 3);  // bijective XCD swizzle, 512=8x64
  const int rb = wg >> 4, cb = wg & 15;
  const int row0 = rb * 320, col0 = cb * 64;
  const int wm = wid >> 1, wn = wid & 1;     // wave tile: 80 rows x 32 cols
  const int l15 = lane & 15, lg = lane >> 4;
  const int srow = lane >> 2;
  const int sk = (lane & 3) ^ ((lane >> 3) & 3);  // inverse-swizzled src slot

  f32x4 acc[5][2];
#pragma unroll
  for (int i = 0; i < 5; ++i)
#pragma unroll
    for (int j = 0; j < 2; ++j) acc[i][j] = (f32x4){0.f, 0.f, 0.f, 0.f};

  auto STAGE = [&](int buf, int ks) {
#pragma unroll
    for (int j = 0; j < 3; ++j) {
      const int g = wid * 3 + j;  // 0..23, wave-uniform
      if (g < 20) {               // A: rows g*16..g*16+15
        const unsigned char* src =
            a8 + (size_t)(row0 + g * 16 + srow) * 768 + ks * 64 + sk * 16;
        __builtin_amdgcn_global_load_lds(
            (const __attribute__((address_space(1))) unsigned int*)src,
            (__attribute__((address_space(3))) unsigned int*)&As[buf][g * 1024],
            16, 0, 0);
      } else {                    // B: rows (g-20)*16..+15
        const unsigned char* src =
            c8 + (size_t)(col0 + (g - 20) * 16 + srow) * 768 + ks * 64 + sk * 16;
        __builtin_amdgcn_global_load_lds(
            (const __attribute__((address_space(1))) unsigned int*)src,
            (__attribute__((address_space(3))) unsigned int*)&Bs[buf][(g - 20) * 1024],
            16, 0, 0);
      }
    }
  };
  auto ldA = [&](int buf, int kh, int fr) -> long long {
    const int row = wm * 80 + fr * 16 + l15;
    const int slot = (kh * 2 + (lg >> 1)) ^ ((row >> 1) & 3);
    return *(const long long*)&As[buf][row * 64 + slot * 16 + (lg & 1) * 8];
  };
  auto ldB = [&](int buf, int kh, int fc) -> long long {
    const int row = wn * 32 + fc * 16 + l15;
    const int slot = (kh * 2 + (lg >> 1)) ^ ((row >> 1) & 3);
    return *(const long long*)&Bs[buf][row * 64 + slot * 16 + (lg & 1) * 8];
  };
  auto COMPUTE = [&](int buf) {
    long long af[5][2], bf[2][2];
#pragma unroll
    for (int fc = 0; fc < 2; ++fc)
#pragma unroll
      for (int kh = 0; kh < 2; ++kh) bf[fc][kh] = ldB(buf, kh, fc);
#pragma unroll
    for (int fr = 0; fr < 5; ++fr)
#pragma unroll
      for (int kh = 0; kh < 2; ++kh) af[fr][kh] = ldA(buf, kh, fr);
    __builtin_amdgcn_s_setprio(1);
#pragma unroll
    for (int kh = 0; kh < 2; ++kh)
#pragma unroll
      for (int fr = 0; fr < 5; ++fr)
#pragma unroll
        for (int fc = 0; fc < 2; ++fc)
          acc[fr][fc] = __builtin_amdgcn_mfma_f32_16x16x32_fp8_fp8(
              af[fr][kh], bf[fc][kh], acc[fr][fc], 0, 0, 0);
    __builtin_amdgcn_s_setprio(0);
  };

  STAGE(0, 0);
#pragma unroll
  for (int s = 0; s < 12; ++s) {
    if (s < 11) {
      STAGE((s + 1) & 1, s + 1);  // buf free per iter s-1's trailing barrier
      asm volatile("s_waitcnt vmcnt(3)" ::: "memory");  // tile s landed
    } else {
      asm volatile("s_waitcnt vmcnt(0)" ::: "memory");
    }
    __builtin_amdgcn_s_barrier();
    COMPUTE(s & 1);
    if (s < 11) __builtin_amdgcn_s_barrier();  // all waves done with buf[s&1]
  }

  // Epilogue: vv = w*cos (diagonal: fp32 sim_own); rowsum[grow] += sum_j exp(vv)
  // |vv| <= ~10.1 -> exp fp32-safe without max subtraction; bias b cancels.
  const float wv = wp[0];
  const int R0 = row0 + wm * 80, C0 = col0 + wn * 32;
#pragma unroll
  for (int fr = 0; fr < 5; ++fr) {
#pragma unroll
    for (int r = 0; r < 4; ++r) {
      const int grow = R0 + fr * 16 + lg * 4 + r;
      const int ownc = grow / 10;  // own speaker column
      float sm = 0.f;
#pragma unroll
      for (int fc = 0; fc < 2; ++fc) {
        const int gcol = C0 + fc * 16 + l15;
        float vv = wv * acc[fr][fc][r];
        if (gcol == ownc) vv = wv * simown[grow];
        sm += __expf(vv);
      }
#pragma unroll
      for (int off = 1; off < 16; off <<= 1) sm += __shfl_xor(sm, off, 16);
      if (l15 == 0) atomicAdd(&rowsum[grow], sm);
    }
  }
}

// ---------------------------------------------------------------------------
// Kernel C: loss_i = log(rowsum_i) - w*simown_i; sum over 10240 into d_out.
// ---------------------------------------------------------------------------
__global__ void __launch_bounds__(256) ge2e_final(
    const float* __restrict__ rowsum, const float* __restrict__ simown,
    const float* __restrict__ wp, float* __restrict__ out) {
  const int i = blockIdx.x * 256 + threadIdx.x;  // 0..10239
  const float wv = wp[0];
  float loss = logf(rowsum[i]) - wv * simown[i];
#pragma unroll
  for (int off = 32; off >= 1; off >>= 1) loss += __shfl_xor(loss, off);
  __shared__ float red[4];
  const int lane = threadIdx.x & 63, wid = threadIdx.x >> 6;
  if (lane == 0) red[wid] = loss;
  __syncthreads();
  if (threadIdx.x == 0) atomicAdd(out, red[0] + red[1] + red[2] + red[3]);
}

extern "C" void kernel_launch(void* const* d_in, const int* in_sizes, int n_in,
                              void* d_out, int out_size, void* d_ws, size_t ws_size,
                              hipStream_t stream) {
  (void)in_sizes; (void)n_in; (void)out_size; (void)ws_size;
  const float* dv = (const float*)d_in[0];
  const float* wp = (const float*)d_in[1];
  // d_in[2] (bias b) cancels exactly in -log_softmax[own]; unused.

  unsigned char* a8 = (unsigned char*)d_ws;                         // 7,864,320 B
  unsigned char* c8 = (unsigned char*)d_ws + 7864320;               //   786,432 B
  float* simown = (float*)((char*)d_ws + 8650752);                  //    40,960 B
  float* rowsum = (float*)((char*)d_ws + 8691712);                  //    40,960 B
  float* out = (float*)d_out;

  ge2e_pre<<<256, 256, 0, stream>>>(dv, (unsigned int*)a8, (unsigned int*)c8,
                                    simown, rowsum, out);
  ge2e_gemm<<<512, 512, 0, stream>>>(a8, c8, simown, wp, rowsum);
  ge2e_final<<<40, 256, 0, stream>>>(rowsum, simown, wp, out);
}